// Round 1
// baseline (157.813 us; speedup 1.0000x reference)
//
#include <hip/hip_runtime.h>
#include <math.h>

#define EPSQ 1e-12f

constexpr int B_N = 64;
constexpr int D_N = 10;
constexpr int P_N = 4096;
constexpr int I_N = 8;
constexpr int O_N = 16;

constexpr int NBT   = 4;              // b tiles (64/16)
constexpr int BTILE = 16;             // b per block
constexpr int BT    = 4;              // b per thread
constexpr int NPC   = 16;             // p chunks
constexpr int PCHUNK = P_N / NPC;     // 256
constexpr int NIT   = PCHUNK / 64;    // 4
constexpr int LROW  = 132;            // padded LDS row stride in dwords (128 + 4)

__device__ __forceinline__ float dot8(float4 a0, float4 a1, float4 b0, float4 b1) {
  return a0.x*b0.x + a0.y*b0.y + a0.z*b0.z + a0.w*b0.w
       + a1.x*b1.x + a1.y*b1.y + a1.z*b1.z + a1.w*b1.w;
}

// part_s layout: [d][bt][pc][bl(16)][o(16)]   (one slot per block x 256)
// part_z layout: [d][bt][pc][bl(16)]
template<int MODE>
__global__ __launch_bounds__(256, 2)
void caps_pass(const float* __restrict__ x, const float* __restrict__ W,
               const float* __restrict__ ps0, const float* __restrict__ ps1,
               const float* __restrict__ pz1,
               float* __restrict__ ps_out, float* __restrict__ pz_out)
{
  __shared__ __align__(16) float wlds[64 * LROW];   // ~33.8 KB
  __shared__ __align__(16) float vlds[BTILE][O_N];  // routing vector w = v0 (+v1)

  const int bid  = blockIdx.x;
  const int d    = bid / (NBT * NPC);
  const int rm   = bid % (NBT * NPC);
  const int bt   = rm / NPC;
  const int pc   = rm % NPC;
  const int t    = threadIdx.x;
  const int lane = t & 63;
  const int bg   = t >> 6;

  // ---- redundantly reduce previous-pass partials -> routing vector in vlds ----
  if (MODE >= 1) {
    const int bl = t >> 4;     // 0..15
    const int o  = t & 15;     // 0..15
    float s0 = 0.f;
    #pragma unroll
    for (int c = 0; c < NPC; ++c)
      s0 += ps0[(((d*NBT + bt)*NPC + c)*BTILE + bl)*O_N + o];
    s0 *= (1.0f / P_N);                       // c0 = uniform 1/P
    float sq = s0 * s0;                       // 16-lane o-group reduce
    sq += __shfl_xor(sq, 1);
    sq += __shfl_xor(sq, 2);
    sq += __shfl_xor(sq, 4);
    sq += __shfl_xor(sq, 8);
    float wv = (sq / (1.f + sq)) * s0 / sqrtf(sq + EPSQ);   // v0
    if (MODE == 2) {
      float s1 = 0.f, Z = 0.f;
      #pragma unroll
      for (int c = 0; c < NPC; ++c) {
        s1 += ps1[(((d*NBT + bt)*NPC + c)*BTILE + bl)*O_N + o];
        Z  += pz1[((d*NBT + bt)*NPC + c)*BTILE + bl];
      }
      s1 /= Z;                                // softmax-weighted mean
      float sq1 = s1 * s1;
      sq1 += __shfl_xor(sq1, 1);
      sq1 += __shfl_xor(sq1, 2);
      sq1 += __shfl_xor(sq1, 4);
      sq1 += __shfl_xor(sq1, 8);
      wv += (sq1 / (1.f + sq1)) * s1 / sqrtf(sq1 + EPSQ);   // w = v0 + v1
    }
    vlds[bl][o] = wv;
  }

  float sacc[BT][O_N];
  float Zacc[BT];
  #pragma unroll
  for (int bi = 0; bi < BT; ++bi) {
    Zacc[bi] = 0.f;
    #pragma unroll
    for (int o = 0; o < O_N; ++o) sacc[bi][o] = 0.f;
  }

  const int pbase = pc * PCHUNK;
  for (int it = 0; it < NIT; ++it) {
    const int p0 = pbase + it * 64;
    __syncthreads();   // protect wlds (and cover vlds writes on it==0)

    // ---- stage W[d][p0..p0+64) into LDS, padded rows (conflict-optimal) ----
    const float4* Wg = (const float4*)(W + ((size_t)(d * P_N + p0)) * (O_N * I_N));
    #pragma unroll
    for (int k = 0; k < 8; ++k) {
      const int idx = t + k * 256;     // 2048 float4 total
      const int row = idx >> 5;
      const int col = idx & 31;
      const float4 wv4 = Wg[idx];
      *(float4*)&wlds[row * LROW + col * 4] = wv4;
    }
    __syncthreads();

    const int p = p0 + lane;
    float4 xv0[BT], xv1[BT];
    #pragma unroll
    for (int bi = 0; bi < BT; ++bi) {
      const int b = bt * BTILE + bg * BT + bi;
      const float4* xg = (const float4*)(x) + ((size_t)(b * P_N + p)) * 2;
      xv0[bi] = xg[0];
      xv1[bi] = xg[1];
    }

    // ---- u[b][o] = W[d,p,o,:] . x[b,p,:] ----
    float u[BT][O_N];
    #pragma unroll
    for (int o = 0; o < O_N; ++o) {
      const float4 w0 = *(const float4*)&wlds[lane * LROW + o * 8];
      const float4 w1 = *(const float4*)&wlds[lane * LROW + o * 8 + 4];
      #pragma unroll
      for (int bi = 0; bi < BT; ++bi)
        u[bi][o] = dot8(w0, w1, xv0[bi], xv1[bi]);
    }

    if (MODE == 0) {
      #pragma unroll
      for (int bi = 0; bi < BT; ++bi)
        #pragma unroll
        for (int o = 0; o < O_N; ++o) sacc[bi][o] += u[bi][o];
    } else {
      float dt[BT] = {0.f, 0.f, 0.f, 0.f};
      #pragma unroll
      for (int oc = 0; oc < 4; ++oc) {
        #pragma unroll
        for (int bi = 0; bi < BT; ++bi) {
          const float4 vv = *(const float4*)&vlds[bg * BT + bi][oc * 4]; // broadcast
          dt[bi] += vv.x * u[bi][oc*4+0] + vv.y * u[bi][oc*4+1]
                  + vv.z * u[bi][oc*4+2] + vv.w * u[bi][oc*4+3];
        }
      }
      #pragma unroll
      for (int bi = 0; bi < BT; ++bi) {
        const float e = expf(dt[bi]);   // b ~ 1e-6: no max-subtraction needed (cancels in s/Z)
        Zacc[bi] += e;
        #pragma unroll
        for (int o = 0; o < O_N; ++o) sacc[bi][o] += e * u[bi][o];
      }
    }
  }

  // ---- reduce across the 64 p-lanes of each wave, lane 0 writes partials ----
  const int pb = (d * NBT + bt) * NPC + pc;
  #pragma unroll
  for (int bi = 0; bi < BT; ++bi) {
    if (MODE >= 1) {
      float z = Zacc[bi];
      z += __shfl_xor(z, 1);  z += __shfl_xor(z, 2);
      z += __shfl_xor(z, 4);  z += __shfl_xor(z, 8);
      z += __shfl_xor(z, 16); z += __shfl_xor(z, 32);
      if (lane == 0) pz_out[pb * BTILE + bg * BT + bi] = z;
    }
    #pragma unroll
    for (int o = 0; o < O_N; ++o) {
      float v = sacc[bi][o];
      v += __shfl_xor(v, 1);  v += __shfl_xor(v, 2);
      v += __shfl_xor(v, 4);  v += __shfl_xor(v, 8);
      v += __shfl_xor(v, 16); v += __shfl_xor(v, 32);
      if (lane == 0) ps_out[(pb * BTILE + bg * BT + bi) * O_N + o] = v;
    }
  }
}

__global__ void caps_final(const float* __restrict__ ps2, const float* __restrict__ pz2,
                           float* __restrict__ out)
{
  const int idx = blockIdx.x * blockDim.x + threadIdx.x;
  if (idx >= B_N * D_N) return;
  const int b  = idx / D_N;
  const int d  = idx % D_N;
  const int bt = b >> 4;
  const int bl = b & 15;
  float s[O_N];
  #pragma unroll
  for (int o = 0; o < O_N; ++o) s[o] = 0.f;
  float Z = 0.f;
  for (int c = 0; c < NPC; ++c) {
    const int pb = (d * NBT + bt) * NPC + c;
    Z += pz2[pb * BTILE + bl];
    #pragma unroll
    for (int o = 0; o < O_N; ++o) s[o] += ps2[(pb * BTILE + bl) * O_N + o];
  }
  float sq = 0.f;
  #pragma unroll
  for (int o = 0; o < O_N; ++o) { s[o] /= Z; sq += s[o] * s[o]; }
  const float scale = sq / (1.f + sq);
  const float inv   = 1.f / sqrtf(sq + EPSQ);
  #pragma unroll
  for (int o = 0; o < O_N; ++o) out[(b * D_N + d) * O_N + o] = scale * s[o] * inv;
}

extern "C" void kernel_launch(void* const* d_in, const int* in_sizes, int n_in,
                              void* d_out, int out_size, void* d_ws, size_t ws_size,
                              hipStream_t stream)
{
  const float* x = (const float*)d_in[0];
  const float* W = (const float*)d_in[1];
  float* out = (float*)d_out;
  float* ws  = (float*)d_ws;

  const size_t PS = (size_t)D_N * NBT * NPC * BTILE * O_N;  // 163840 floats
  const size_t PZ = (size_t)D_N * NBT * NPC * BTILE;        // 10240 floats
  float* ps0 = ws;
  float* ps1 = ps0 + PS;
  float* pz1 = ps1 + PS;
  float* ps2 = pz1 + PZ;
  float* pz2 = ps2 + PS;
  // total ws use: (3*PS + 2*PZ)*4 B ~= 2.05 MB

  dim3 blk(256);
  dim3 grid(D_N * NBT * NPC);  // 640 blocks
  hipLaunchKernelGGL((caps_pass<0>), grid, blk, 0, stream,
                     x, W, nullptr, nullptr, nullptr, ps0, nullptr);
  hipLaunchKernelGGL((caps_pass<1>), grid, blk, 0, stream,
                     x, W, ps0, nullptr, nullptr, ps1, pz1);
  hipLaunchKernelGGL((caps_pass<2>), grid, blk, 0, stream,
                     x, W, ps0, ps1, pz1, ps2, pz2);
  hipLaunchKernelGGL(caps_final, dim3(10), dim3(64), 0, stream, ps2, pz2, out);
}